// Round 1
// baseline (602.434 us; speedup 1.0000x reference)
//
#include <hip/hip_runtime.h>
#include <hip/hip_bf16.h>
#include <math.h>

#define B 32
#define P 100
#define N 1000
#define D 128

constexpr float SQRT_D_INV = 1.0f / 11.313708498984761f;
constexpr float CLIPV = 10.0f;

// ---------------------------------------------------------------------------
// K1: k = nodes @ Wk^T, v = nodes @ Wv^T, ek = exp(k), ekv = ek*v
// grid: (B*N)/R1 blocks, 128 threads (thread = output dim d)
// ---------------------------------------------------------------------------
#define R1 32
__global__ void kv_kernel(const float* __restrict__ nodes,
                          const float* __restrict__ Wk,
                          const float* __restrict__ Wv,
                          float* __restrict__ ek,
                          float* __restrict__ ekv) {
    __shared__ float sh[R1][D];
    const int t = threadIdx.x;                 // d
    const long row0 = (long)blockIdx.x * R1;   // flat row in [0, B*N)

    // stage R1 input rows (R1*D floats) into LDS, float4 coalesced
    const float4* src = (const float4*)(nodes + row0 * D);
    float4* dst = (float4*)(&sh[0][0]);
    #pragma unroll
    for (int i = 0; i < (R1 * D / 4) / 128; ++i)
        dst[t + i * 128] = src[t + i * 128];
    __syncthreads();

    float ak[R1], av[R1];
    #pragma unroll
    for (int r = 0; r < R1; ++r) { ak[r] = 0.f; av[r] = 0.f; }

    const float* wkrow = Wk + t * D;
    const float* wvrow = Wv + t * D;
    for (int e = 0; e < D; ++e) {
        float wk = wkrow[e];
        float wv = wvrow[e];
        #pragma unroll
        for (int r = 0; r < R1; ++r) {
            ak[r] = fmaf(sh[r][e], wk, ak[r]);
            av[r] = fmaf(sh[r][e], wv, av[r]);
        }
    }
    #pragma unroll
    for (int r = 0; r < R1; ++r) {
        float e = __expf(ak[r]);
        long off = (row0 + r) * D + t;
        ek[off] = e;
        ekv[off] = e * av[r];
    }
}

// ---------------------------------------------------------------------------
// K2: qsig = sigmoid(q1 @ Wqf^T + qlast @ Wql^T)
// grid: (B*P)/R2 blocks, 128 threads
// ---------------------------------------------------------------------------
#define R2 16
__global__ void q_kernel(const float* __restrict__ q1,
                         const float* __restrict__ qlast,
                         const float* __restrict__ Wqf,
                         const float* __restrict__ Wql,
                         float* __restrict__ qsig) {
    __shared__ float sh1[R2][D];
    __shared__ float sh2[R2][D];
    const int t = threadIdx.x;
    const long row0 = (long)blockIdx.x * R2;   // flat row in [0, B*P)

    const float4* s1 = (const float4*)(q1 + row0 * D);
    const float4* s2 = (const float4*)(qlast + row0 * D);
    float4* d1 = (float4*)(&sh1[0][0]);
    float4* d2 = (float4*)(&sh2[0][0]);
    #pragma unroll
    for (int i = 0; i < (R2 * D / 4) / 128; ++i) {
        d1[t + i * 128] = s1[t + i * 128];
        d2[t + i * 128] = s2[t + i * 128];
    }
    __syncthreads();

    float acc[R2];
    #pragma unroll
    for (int r = 0; r < R2; ++r) acc[r] = 0.f;

    const float* wf = Wqf + t * D;
    const float* wl = Wql + t * D;
    for (int e = 0; e < D; ++e) {
        float a = wf[e];
        float c = wl[e];
        #pragma unroll
        for (int r = 0; r < R2; ++r) {
            acc[r] = fmaf(sh1[r][e], a, acc[r]);
            acc[r] = fmaf(sh2[r][e], c, acc[r]);
        }
    }
    #pragma unroll
    for (int r = 0; r < R2; ++r) {
        float s = 1.0f / (1.0f + __expf(-acc[r]));
        qsig[(row0 + r) * D + t] = s;
    }
}

// ---------------------------------------------------------------------------
// K3: num = ebias @ ekv, den = ebias @ ek, aft = qsig * num / den
// ebias[b,p,n] = exp(-ls*alpha*cur_dist + ninf)
// grid: B * (P/PT) blocks, 128 threads (thread = d)
// ---------------------------------------------------------------------------
#define PT 10
__global__ void aft_kernel(const float* __restrict__ cur_dist,
                           const float* __restrict__ ninf,
                           const float* __restrict__ ek,
                           const float* __restrict__ ekv,
                           const float* __restrict__ qsig,
                           const float* __restrict__ log_scale,
                           const float* __restrict__ aft_alpha,
                           float* __restrict__ aft) {
    __shared__ float eb[PT][128];
    const int t = threadIdx.x;                 // d
    const int b = blockIdx.x / (P / PT);
    const int p0 = (blockIdx.x % (P / PT)) * PT;
    const float lsA = log_scale[0] * aft_alpha[0];

    float num[PT], den[PT];
    #pragma unroll
    for (int i = 0; i < PT; ++i) { num[i] = 0.f; den[i] = 0.f; }

    for (int nc = 0; nc < N; nc += 128) {
        int n = nc + t;
        #pragma unroll
        for (int i = 0; i < PT; ++i) {
            float e = 0.f;
            if (n < N) {
                long idx = ((long)b * P + p0 + i) * N + n;
                e = __expf(fmaf(-lsA, cur_dist[idx], ninf[idx]));
            }
            eb[i][t] = e;
        }
        __syncthreads();
        int lim = min(128, N - nc);
        for (int j = 0; j < lim; ++j) {
            long off = ((long)b * N + nc + j) * D + t;
            float ekn = ek[off];
            float evn = ekv[off];
            #pragma unroll
            for (int i = 0; i < PT; ++i) {
                float e = eb[i][j];
                num[i] = fmaf(e, evn, num[i]);
                den[i] = fmaf(e, ekn, den[i]);
            }
        }
        __syncthreads();
    }
    #pragma unroll
    for (int i = 0; i < PT; ++i) {
        long o = ((long)b * P + p0 + i) * D + t;
        aft[o] = qsig[o] * num[i] / den[i];
    }
}

// ---------------------------------------------------------------------------
// K4: score = clip*tanh(aft.nodes/sqrtD - ls*alpha*cur_dist) + ninf; softmax_n
// grid: B * (P/PT2) blocks, 256 threads (thread handles NL node indices)
// ---------------------------------------------------------------------------
#define PT2 10
#define NL 4   // ceil(1000/256)
__global__ void score_kernel(const float* __restrict__ aft,
                             const float* __restrict__ nodes,
                             const float* __restrict__ cur_dist,
                             const float* __restrict__ ninf,
                             const float* __restrict__ log_scale,
                             const float* __restrict__ dist_alpha,
                             float* __restrict__ out) {
    __shared__ float sa[PT2][D];
    __shared__ float red[4];
    __shared__ float bval;
    const int t = threadIdx.x;
    const int b = blockIdx.x / (P / PT2);
    const int p0 = (blockIdx.x % (P / PT2)) * PT2;
    const float lsA = log_scale[0] * dist_alpha[0];

    // stage PT2 aft rows into LDS
    const float4* src = (const float4*)(aft + ((long)b * P + p0) * D);
    float4* dst = (float4*)(&sa[0][0]);
    for (int i = t; i < PT2 * D / 4; i += 256) dst[i] = src[i];
    __syncthreads();

    float s[NL][PT2];
    for (int j = 0; j < NL; ++j) {
        int n = t + j * 256;
        if (n < N) {
            const float4* nrow = (const float4*)(nodes + ((long)b * N + n) * D);
            float acc[PT2];
            #pragma unroll
            for (int i = 0; i < PT2; ++i) acc[i] = 0.f;
            for (int e4 = 0; e4 < D / 4; ++e4) {
                float4 x = nrow[e4];
                #pragma unroll
                for (int i = 0; i < PT2; ++i) {
                    acc[i] = fmaf(x.x, sa[i][e4 * 4 + 0], acc[i]);
                    acc[i] = fmaf(x.y, sa[i][e4 * 4 + 1], acc[i]);
                    acc[i] = fmaf(x.z, sa[i][e4 * 4 + 2], acc[i]);
                    acc[i] = fmaf(x.w, sa[i][e4 * 4 + 3], acc[i]);
                }
            }
            #pragma unroll
            for (int i = 0; i < PT2; ++i) {
                long idx = ((long)b * P + p0 + i) * N + n;
                float sc = fmaf(acc[i], SQRT_D_INV, -lsA * cur_dist[idx]);
                sc = CLIPV * tanhf(sc) + ninf[idx];
                s[j][i] = sc;
            }
        } else {
            #pragma unroll
            for (int i = 0; i < PT2; ++i) s[j][i] = -INFINITY;
        }
    }

    // per-p softmax over n (block-wide reductions)
    const int wid = t >> 6;
    for (int i = 0; i < PT2; ++i) {
        float m = -INFINITY;
        #pragma unroll
        for (int j = 0; j < NL; ++j) m = fmaxf(m, s[j][i]);
        #pragma unroll
        for (int o = 1; o < 64; o <<= 1) m = fmaxf(m, __shfl_xor(m, o, 64));
        if ((t & 63) == 0) red[wid] = m;
        __syncthreads();
        if (t == 0) bval = fmaxf(fmaxf(red[0], red[1]), fmaxf(red[2], red[3]));
        __syncthreads();
        m = bval;

        float ssum = 0.f;
        #pragma unroll
        for (int j = 0; j < NL; ++j) {
            float e = (s[j][i] > -1e30f) ? __expf(s[j][i] - m) : 0.f;
            s[j][i] = e;
            ssum += e;
        }
        #pragma unroll
        for (int o = 1; o < 64; o <<= 1) ssum += __shfl_xor(ssum, o, 64);
        if ((t & 63) == 0) red[wid] = ssum;
        __syncthreads();
        if (t == 0) bval = red[0] + red[1] + red[2] + red[3];
        __syncthreads();
        float inv = 1.0f / bval;
        #pragma unroll
        for (int j = 0; j < NL; ++j) {
            int n = t + j * 256;
            if (n < N) out[((long)b * P + p0 + i) * N + n] = s[j][i] * inv;
        }
        __syncthreads();
    }
}

// ---------------------------------------------------------------------------
extern "C" void kernel_launch(void* const* d_in, const int* in_sizes, int n_in,
                              void* d_out, int out_size, void* d_ws, size_t ws_size,
                              hipStream_t stream) {
    const float* nodes      = (const float*)d_in[0];
    const float* q1         = (const float*)d_in[1];
    const float* qlast      = (const float*)d_in[2];
    const float* cur_dist   = (const float*)d_in[3];
    const float* ninf       = (const float*)d_in[4];
    const float* log_scale  = (const float*)d_in[5];
    const float* Wqf        = (const float*)d_in[6];
    const float* Wql        = (const float*)d_in[7];
    const float* Wk         = (const float*)d_in[8];
    const float* Wv         = (const float*)d_in[9];
    const float* dist_alpha = (const float*)d_in[10];
    const float* aft_alpha  = (const float*)d_in[11];
    float* out = (float*)d_out;

    float* ws   = (float*)d_ws;
    float* ek   = ws;                          // B*N*D
    float* ekv  = ek  + (long)B * N * D;       // B*N*D
    float* qsig = ekv + (long)B * N * D;       // B*P*D
    float* aft  = qsig + (long)B * P * D;      // B*P*D

    kv_kernel<<<(B * N) / R1, 128, 0, stream>>>(nodes, Wk, Wv, ek, ekv);
    q_kernel<<<(B * P) / R2, 128, 0, stream>>>(q1, qlast, Wqf, Wql, qsig);
    aft_kernel<<<B * (P / PT), 128, 0, stream>>>(cur_dist, ninf, ek, ekv, qsig,
                                                 log_scale, aft_alpha, aft);
    score_kernel<<<B * (P / PT2), 256, 0, stream>>>(aft, nodes, cur_dist, ninf,
                                                    log_scale, dist_alpha, out);
}

// Round 2
// 301.249 us; speedup vs baseline: 1.9998x; 1.9998x over previous
//
#include <hip/hip_runtime.h>
#include <hip/hip_bf16.h>
#include <math.h>

#define B 32
#define P 100
#define N 1000
#define D 128

constexpr float SQRT_D_INV = 1.0f / 11.313708498984761f;
constexpr float CLIPV = 10.0f;

// ---------------------------------------------------------------------------
// K1: k = nodes @ Wk^T, v = nodes @ Wv^T, ek = exp(k), ekv = ek*v
// grid: (B*N)/R1 blocks, 128 threads (thread = output dim d)
// ---------------------------------------------------------------------------
#define R1 32
__global__ void kv_kernel(const float* __restrict__ nodes,
                          const float* __restrict__ Wk,
                          const float* __restrict__ Wv,
                          float* __restrict__ ek,
                          float* __restrict__ ekv) {
    __shared__ float sh[R1][D];
    const int t = threadIdx.x;                 // d
    const long row0 = (long)blockIdx.x * R1;   // flat row in [0, B*N)

    const float4* src = (const float4*)(nodes + row0 * D);
    float4* dst = (float4*)(&sh[0][0]);
    #pragma unroll
    for (int i = 0; i < (R1 * D / 4) / 128; ++i)
        dst[t + i * 128] = src[t + i * 128];
    __syncthreads();

    float ak[R1], av[R1];
    #pragma unroll
    for (int r = 0; r < R1; ++r) { ak[r] = 0.f; av[r] = 0.f; }

    const float* wkrow = Wk + t * D;
    const float* wvrow = Wv + t * D;
    for (int e = 0; e < D; ++e) {
        float wk = wkrow[e];
        float wv = wvrow[e];
        #pragma unroll
        for (int r = 0; r < R1; ++r) {
            ak[r] = fmaf(sh[r][e], wk, ak[r]);
            av[r] = fmaf(sh[r][e], wv, av[r]);
        }
    }
    #pragma unroll
    for (int r = 0; r < R1; ++r) {
        float e = __expf(ak[r]);
        long off = (row0 + r) * D + t;
        ek[off] = e;
        ekv[off] = e * av[r];
    }
}

// ---------------------------------------------------------------------------
// K2: qsig = sigmoid(q1 @ Wqf^T + qlast @ Wql^T)
// ---------------------------------------------------------------------------
#define R2 16
__global__ void q_kernel(const float* __restrict__ q1,
                         const float* __restrict__ qlast,
                         const float* __restrict__ Wqf,
                         const float* __restrict__ Wql,
                         float* __restrict__ qsig) {
    __shared__ float sh1[R2][D];
    __shared__ float sh2[R2][D];
    const int t = threadIdx.x;
    const long row0 = (long)blockIdx.x * R2;

    const float4* s1 = (const float4*)(q1 + row0 * D);
    const float4* s2 = (const float4*)(qlast + row0 * D);
    float4* d1 = (float4*)(&sh1[0][0]);
    float4* d2 = (float4*)(&sh2[0][0]);
    #pragma unroll
    for (int i = 0; i < (R2 * D / 4) / 128; ++i) {
        d1[t + i * 128] = s1[t + i * 128];
        d2[t + i * 128] = s2[t + i * 128];
    }
    __syncthreads();

    float acc[R2];
    #pragma unroll
    for (int r = 0; r < R2; ++r) acc[r] = 0.f;

    const float* wf = Wqf + t * D;
    const float* wl = Wql + t * D;
    for (int e = 0; e < D; ++e) {
        float a = wf[e];
        float c = wl[e];
        #pragma unroll
        for (int r = 0; r < R2; ++r) {
            acc[r] = fmaf(sh1[r][e], a, acc[r]);
            acc[r] = fmaf(sh2[r][e], c, acc[r]);
        }
    }
    #pragma unroll
    for (int r = 0; r < R2; ++r) {
        float s = 1.0f / (1.0f + __expf(-acc[r]));
        qsig[(row0 + r) * D + t] = s;
    }
}

// ---------------------------------------------------------------------------
// K3a: partial num/den over an n-chunk.
// block = (b, p-tile of PT, chunk c of NC); 128 threads (thread = d).
// pnum/pden layout: [c][b][p][d] for coalesced reduce.
// ---------------------------------------------------------------------------
#define PT 20
__global__ void aft_part_kernel(const float* __restrict__ cur_dist,
                                const float* __restrict__ ninf,
                                const float* __restrict__ ek,
                                const float* __restrict__ ekv,
                                const float* __restrict__ log_scale,
                                const float* __restrict__ aft_alpha,
                                float* __restrict__ pnum,
                                float* __restrict__ pden,
                                int NC) {
    __shared__ float eb[PT][128];
    const int t = threadIdx.x;                 // d
    const int c  = blockIdx.x % NC;
    const int pt = (blockIdx.x / NC) % (P / PT);
    const int b  = blockIdx.x / (NC * (P / PT));
    const int p0 = pt * PT;
    const int L = (N + NC - 1) / NC;
    const int n_begin = c * L;
    const int n_end = min(N, n_begin + L);
    const float lsA = log_scale[0] * aft_alpha[0];

    float num[PT], den[PT];
    #pragma unroll
    for (int i = 0; i < PT; ++i) { num[i] = 0.f; den[i] = 0.f; }

    for (int nc0 = n_begin; nc0 < n_end; nc0 += 128) {
        int n = nc0 + t;
        #pragma unroll
        for (int i = 0; i < PT; ++i) {
            float e = 0.f;
            if (n < n_end) {
                long idx = ((long)b * P + p0 + i) * N + n;
                e = __expf(fmaf(-lsA, cur_dist[idx], ninf[idx]));
            }
            eb[i][t] = e;
        }
        __syncthreads();
        int lim = min(128, n_end - nc0);
        for (int j = 0; j < lim; ++j) {
            long off = ((long)b * N + nc0 + j) * D + t;
            float ekn = ek[off];
            float evn = ekv[off];
            #pragma unroll
            for (int i = 0; i < PT; ++i) {
                float e = eb[i][j];
                num[i] = fmaf(e, evn, num[i]);
                den[i] = fmaf(e, ekn, den[i]);
            }
        }
        __syncthreads();
    }
    #pragma unroll
    for (int i = 0; i < PT; ++i) {
        long o = (((long)c * B + b) * P + p0 + i) * D + t;
        pnum[o] = num[i];
        pden[o] = den[i];
    }
}

// ---------------------------------------------------------------------------
// K3b: reduce chunks, aft = qsig * num / den.  1 thread per (b,p,d).
// ---------------------------------------------------------------------------
__global__ void aft_reduce_kernel(const float* __restrict__ pnum,
                                  const float* __restrict__ pden,
                                  const float* __restrict__ qsig,
                                  float* __restrict__ aft,
                                  int NC) {
    const long i = (long)blockIdx.x * 256 + threadIdx.x;  // < B*P*D
    const long BPD = (long)B * P * D;
    float n = 0.f, d = 0.f;
    for (int c = 0; c < NC; ++c) {
        n += pnum[(long)c * BPD + i];
        d += pden[(long)c * BPD + i];
    }
    aft[i] = qsig[i] * n / d;
}

// ---------------------------------------------------------------------------
// K4a: raw clipped scores into out.
// block = (b, p-tile of PT2, chunk of SC); 256 threads (thread = n).
// ---------------------------------------------------------------------------
#define PT2 10
#define SC 4
__global__ void score_part_kernel(const float* __restrict__ aft,
                                  const float* __restrict__ nodes,
                                  const float* __restrict__ cur_dist,
                                  const float* __restrict__ ninf,
                                  const float* __restrict__ log_scale,
                                  const float* __restrict__ dist_alpha,
                                  float* __restrict__ out) {
    __shared__ float sa[PT2][D];
    const int t = threadIdx.x;
    const int c  = blockIdx.x % SC;
    const int pt = (blockIdx.x / SC) % (P / PT2);
    const int b  = blockIdx.x / (SC * (P / PT2));
    const int p0 = pt * PT2;
    const int L = (N + SC - 1) / SC;               // 250
    const int n_begin = c * L;
    const int n_end = min(N, n_begin + L);
    const float lsA = log_scale[0] * dist_alpha[0];

    const float4* src = (const float4*)(aft + ((long)b * P + p0) * D);
    float4* dst = (float4*)(&sa[0][0]);
    for (int i = t; i < PT2 * D / 4; i += 256) dst[i] = src[i];
    __syncthreads();

    for (int n = n_begin + t; n < n_end; n += 256) {
        const float4* nrow = (const float4*)(nodes + ((long)b * N + n) * D);
        float acc[PT2];
        #pragma unroll
        for (int i = 0; i < PT2; ++i) acc[i] = 0.f;
        for (int e4 = 0; e4 < D / 4; ++e4) {
            float4 x = nrow[e4];
            #pragma unroll
            for (int i = 0; i < PT2; ++i) {
                acc[i] = fmaf(x.x, sa[i][e4 * 4 + 0], acc[i]);
                acc[i] = fmaf(x.y, sa[i][e4 * 4 + 1], acc[i]);
                acc[i] = fmaf(x.z, sa[i][e4 * 4 + 2], acc[i]);
                acc[i] = fmaf(x.w, sa[i][e4 * 4 + 3], acc[i]);
            }
        }
        #pragma unroll
        for (int i = 0; i < PT2; ++i) {
            long idx = ((long)b * P + p0 + i) * N + n;
            float sc = fmaf(acc[i], SQRT_D_INV, -lsA * cur_dist[idx]);
            out[idx] = CLIPV * tanhf(sc) + ninf[idx];
        }
    }
}

// ---------------------------------------------------------------------------
// K4b: in-place row softmax over n.  block per (b,p) row; 256 threads.
// ---------------------------------------------------------------------------
#define NL 4
__global__ void softmax_kernel(float* __restrict__ out) {
    __shared__ float red[4];
    __shared__ float bval;
    const int t = threadIdx.x;
    const int wid = t >> 6;
    float* r = out + (long)blockIdx.x * N;

    float v[NL];
    float m = -INFINITY;
    #pragma unroll
    for (int j = 0; j < NL; ++j) {
        int n = t + j * 256;
        v[j] = (n < N) ? r[n] : -INFINITY;
        m = fmaxf(m, v[j]);
    }
    #pragma unroll
    for (int o = 1; o < 64; o <<= 1) m = fmaxf(m, __shfl_xor(m, o, 64));
    if ((t & 63) == 0) red[wid] = m;
    __syncthreads();
    if (t == 0) bval = fmaxf(fmaxf(red[0], red[1]), fmaxf(red[2], red[3]));
    __syncthreads();
    m = bval;

    float ssum = 0.f;
    #pragma unroll
    for (int j = 0; j < NL; ++j) {
        float e = (v[j] > -1e30f) ? __expf(v[j] - m) : 0.f;
        v[j] = e;
        ssum += e;
    }
    #pragma unroll
    for (int o = 1; o < 64; o <<= 1) ssum += __shfl_xor(ssum, o, 64);
    if ((t & 63) == 0) red[wid] = ssum;
    __syncthreads();
    if (t == 0) bval = red[0] + red[1] + red[2] + red[3];
    __syncthreads();
    float inv = 1.0f / bval;
    #pragma unroll
    for (int j = 0; j < NL; ++j) {
        int n = t + j * 256;
        if (n < N) r[n] = v[j] * inv;
    }
}

// ---------------------------------------------------------------------------
extern "C" void kernel_launch(void* const* d_in, const int* in_sizes, int n_in,
                              void* d_out, int out_size, void* d_ws, size_t ws_size,
                              hipStream_t stream) {
    const float* nodes      = (const float*)d_in[0];
    const float* q1         = (const float*)d_in[1];
    const float* qlast      = (const float*)d_in[2];
    const float* cur_dist   = (const float*)d_in[3];
    const float* ninf       = (const float*)d_in[4];
    const float* log_scale  = (const float*)d_in[5];
    const float* Wqf        = (const float*)d_in[6];
    const float* Wql        = (const float*)d_in[7];
    const float* Wk         = (const float*)d_in[8];
    const float* Wv         = (const float*)d_in[9];
    const float* dist_alpha = (const float*)d_in[10];
    const float* aft_alpha  = (const float*)d_in[11];
    float* out = (float*)d_out;

    const long BND = (long)B * N * D;   // 4,096,000
    const long BPD = (long)B * P * D;   //   409,600

    float* ws   = (float*)d_ws;
    float* ek   = ws;                   // BND
    float* ekv  = ek  + BND;            // BND
    float* qsig = ekv + BND;            // BPD
    float* aft  = qsig + BPD;           // BPD
    float* pnum = aft + BPD;            // NC*BPD
    // NC chosen from available scratch (pnum+pden need 2*NC*BPD floats)
    long avail = (long)(ws_size / 4) - (2 * BND + 2 * BPD);
    int NC = (int)(avail / (2 * BPD));
    if (NC < 1) NC = 1;
    if (NC > 8) NC = 8;
    float* pden = pnum + (long)NC * BPD;

    kv_kernel<<<(B * N) / R1, 128, 0, stream>>>(nodes, Wk, Wv, ek, ekv);
    q_kernel<<<(B * P) / R2, 128, 0, stream>>>(q1, qlast, Wqf, Wql, qsig);
    aft_part_kernel<<<B * (P / PT) * NC, 128, 0, stream>>>(
        cur_dist, ninf, ek, ekv, log_scale, aft_alpha, pnum, pden, NC);
    aft_reduce_kernel<<<(int)(BPD / 256), 256, 0, stream>>>(pnum, pden, qsig, aft, NC);
    score_part_kernel<<<B * (P / PT2) * SC, 256, 0, stream>>>(
        aft, nodes, cur_dist, ninf, log_scale, dist_alpha, out);
    softmax_kernel<<<B * P, 256, 0, stream>>>(out);
}